// Round 2
// baseline (575.085 us; speedup 1.0000x reference)
//
#include <hip/hip_runtime.h>
#include <hip/hip_cooperative_groups.h>

namespace cg = cooperative_groups;

// Problem constants (from reference): N=65536 rows, A=512 features, C=1000 classes.
constexpr int N_ROWS  = 65536;
constexpr int N_FEAT  = 512;
constexpr int N_FEAT2 = N_FEAT / 2;   // float2 per row = 256
constexpr int N_CLS   = 1000;
constexpr int GRID    = 1000;         // one block per class (phase 4); ≤ co-resident capacity
constexpr int BLOCK   = 256;

// Workspace layout (bytes):
//   [0,       4096)   int nc[1024]      per-class counts (zeroed in phase 0)
//   [4096,    8192)   int offs[1024]    exclusive prefix offsets
//   [8192,   12288)   int cursor[1024]  scatter cursors
//   [12288, 274432)   int perm[65536]   row indices grouped by class

__global__ __launch_bounds__(BLOCK) void estimator_all(
    const float* __restrict__ features,
    const int*   __restrict__ labels,
    const float* __restrict__ count,
    const float* __restrict__ mean,
    const float* __restrict__ cov,
    float*       __restrict__ out,
    int* __restrict__ nc,
    int* __restrict__ offs,
    int* __restrict__ cursor,
    int* __restrict__ perm)
{
    cg::grid_group grid = cg::this_grid();
    const int b = blockIdx.x, t = threadIdx.x;
    __shared__ int sh[BLOCK];   // reused: scan partials (phase 2), row staging (phase 4)

    // ---- Phase 0: zero histogram bins (ws is poisoned 0xAA) ----
    if (b == 0)
        for (int i = t; i < 1024; i += BLOCK) nc[i] = 0;
    grid.sync();

    // ---- Phase 1: histogram ----
    for (int i = b * BLOCK + t; i < N_ROWS; i += GRID * BLOCK)
        atomicAdd(&nc[labels[i]], 1);
    grid.sync();

    // ---- Phase 2: exclusive scan over 1024 bins (block 0; 4 bins/thread) ----
    if (b == 0) {
        const int i0 = t * 4;
        int v0 = nc[i0], v1 = nc[i0+1], v2 = nc[i0+2], v3 = nc[i0+3];
        int s = v0 + v1 + v2 + v3;
        sh[t] = s;
        __syncthreads();
        for (int d = 1; d < BLOCK; d <<= 1) {           // Hillis-Steele over 256
            int x = (t >= d) ? sh[t - d] : 0;
            __syncthreads();
            sh[t] += x;
            __syncthreads();
        }
        int o0 = sh[t] - s;
        int o1 = o0 + v0, o2 = o1 + v1, o3 = o2 + v2;
        offs[i0] = o0; offs[i0+1] = o1; offs[i0+2] = o2; offs[i0+3] = o3;
        cursor[i0] = o0; cursor[i0+1] = o1; cursor[i0+2] = o2; cursor[i0+3] = o3;
    }
    grid.sync();

    // ---- Phase 3: scatter row indices grouped by class ----
    for (int i = b * BLOCK + t; i < N_ROWS; i += GRID * BLOCK) {
        int c = labels[i];
        perm[atomicAdd(&cursor[c], 1)] = i;
    }
    grid.sync();

    // ---- Phase 4: per-class reduction + fused epilogue (block b = class b) ----
    const int c = b;
    const int n = nc[c];
    const int start = offs[c];
    const float2* __restrict__ f2 = (const float2*)features;

    float sx = 0.f, sy = 0.f, qx = 0.f, qy = 0.f;
    for (int base = 0; base < n; base += BLOCK) {
        int chunk = min(BLOCK, n - base);
        __syncthreads();
        if (t < chunk) sh[t] = perm[start + base + t];
        __syncthreads();
        #pragma unroll 4
        for (int j = 0; j < chunk; ++j) {
            int r = sh[j];                               // LDS broadcast (free)
            float2 v = f2[(size_t)r * N_FEAT2 + t];      // contiguous 2 KB per block
            sx += v.x; sy += v.y;
            qx += v.x * v.x; qy += v.y * v.y;
        }
    }

    const float fn  = (float)n;
    const float amt = (n > 0) ? fn : 1.0f;
    const float inv = 1.0f / amt;
    const float avx = sx * inv, avy = sy * inv;
    const float vrx = qx * inv - avx * avx;              // E[x^2] - E[x]^2 == segsum((x-ave)^2)/amt
    const float vry = qy * inv - avy * avy;

    const float cnt   = count[c];
    const float denom = fn + cnt;
    const float w     = (denom == 0.f) ? 0.f : fn / denom;
    const float omw   = 1.0f - w;

    const float2 mv = ((const float2*)mean)[c * N_FEAT2 + t];
    const float2 cv = ((const float2*)cov)[c * N_FEAT2 + t];
    const float dx = mv.x - avx, dy = mv.y - avy;

    float2 covn, meann;
    covn.x  = cv.x * omw + vrx * w + w * omw * dx * dx;
    covn.y  = cv.y * omw + vry * w + w * omw * dy * dy;
    meann.x = mv.x * omw + avx * w;
    meann.y = mv.y * omw + avy * w;

    ((float2*)out)[c * N_FEAT2 + t] = covn;                          // cov_new  [C,A]
    ((float2*)(out + N_CLS * N_FEAT))[c * N_FEAT2 + t] = meann;      // mean_new [C,A]
    if (t == 0) out[2 * N_CLS * N_FEAT + c] = cnt + fn;              // count_new [C]
}

extern "C" void kernel_launch(void* const* d_in, const int* in_sizes, int n_in,
                              void* d_out, int out_size, void* d_ws, size_t ws_size,
                              hipStream_t stream) {
    const float* features = (const float*)d_in[0];
    const int*   labels   = (const int*)d_in[1];
    const float* count    = (const float*)d_in[2];
    const float* mean     = (const float*)d_in[3];
    const float* cov      = (const float*)d_in[4];
    float* out = (float*)d_out;

    char* ws = (char*)d_ws;
    int* nc     = (int*)(ws + 0);
    int* offs   = (int*)(ws + 4096);
    int* cursor = (int*)(ws + 8192);
    int* perm   = (int*)(ws + 12288);

    void* args[] = { &features, &labels, &count, &mean, &cov, &out,
                     &nc, &offs, &cursor, &perm };
    hipLaunchCooperativeKernel((const void*)estimator_all,
                               dim3(GRID), dim3(BLOCK), args, 0, stream);
}

// Round 3
// 233.640 us; speedup vs baseline: 2.4614x; 2.4614x over previous
//
#include <hip/hip_runtime.h>

// Problem constants (from reference): N=65536 rows, A=512 features, C=1000 classes.
constexpr int N_ROWS  = 65536;
constexpr int N_FEAT  = 512;
constexpr int N_FEAT2 = N_FEAT / 2;   // float2 per row = 256
constexpr int N_CLS   = 1000;

// Workspace layout (bytes):
//   [0,     8192)   int offs[1025..]   exclusive prefix offsets (offs[c], c<=1000)
//   [8192, 12288)   int cursor[1024]   scatter cursors
//   [12288, ...)    int perm[65536]    row indices grouped by class

// ---- Kernel 1: fused zero + histogram + scan (single block, 1024 threads) ----
__global__ __launch_bounds__(1024) void hist_scan_kernel(
    const int* __restrict__ labels, int* __restrict__ offs, int* __restrict__ cursor)
{
    __shared__ int bins[1024];
    __shared__ int tmp[1024];
    const int t = threadIdx.x;
    bins[t] = 0;
    __syncthreads();

    const int4* __restrict__ l4 = (const int4*)labels;
    #pragma unroll 4
    for (int i = t; i < N_ROWS / 4; i += 1024) {
        int4 v = l4[i];
        atomicAdd(&bins[v.x], 1); atomicAdd(&bins[v.y], 1);
        atomicAdd(&bins[v.z], 1); atomicAdd(&bins[v.w], 1);
    }
    __syncthreads();

    // Hillis-Steele inclusive scan over 1024
    const int v = bins[t];
    tmp[t] = v;
    __syncthreads();
    for (int d = 1; d < 1024; d <<= 1) {
        int x = (t >= d) ? tmp[t - d] : 0;
        __syncthreads();
        tmp[t] += x;
        __syncthreads();
    }
    const int excl = tmp[t] - v;
    offs[t] = excl;      // offs[c+1]-offs[c] == count of class c (bins>=1000 are 0)
    cursor[t] = excl;
    if (t == 0) offs[1024] = N_ROWS;
}

// ---- Kernel 2: scatter row indices grouped by class ----
__global__ __launch_bounds__(256) void scatter_kernel(
    const int* __restrict__ labels, int* __restrict__ cursor, int* __restrict__ perm)
{
    const int i = blockIdx.x * blockDim.x + threadIdx.x;   // one int4 (4 rows) per thread
    const int4 v = ((const int4*)labels)[i];
    const int r = i * 4;
    perm[atomicAdd(&cursor[v.x], 1)] = r + 0;
    perm[atomicAdd(&cursor[v.y], 1)] = r + 1;
    perm[atomicAdd(&cursor[v.z], 1)] = r + 2;
    perm[atomicAdd(&cursor[v.w], 1)] = r + 3;
}

// ---- Kernel 3: per-class reduction + fused epilogue ----
// One block per class; 256 threads, each owns 2 columns (float2).
// Manual unroll-8: 8 independent row loads hoisted per batch -> 8 outstanding
// 512B wave-loads, enough MLP to be BW-bound instead of latency-bound.
__global__ __launch_bounds__(256) void estimator_main(
    const float* __restrict__ features,
    const float* __restrict__ count,
    const float* __restrict__ mean,
    const float* __restrict__ cov,
    const int* __restrict__ offs,
    const int* __restrict__ perm,
    float* __restrict__ out)
{
    const int c = blockIdx.x;
    const int t = threadIdx.x;
    const int start = offs[c];
    const int n = offs[c + 1] - start;

    __shared__ int sh[256];
    const float2* __restrict__ f2 = (const float2*)features;

    float sx = 0.f, sy = 0.f, qx = 0.f, qy = 0.f;

    for (int base = 0; base < n; base += 256) {
        const int chunk = min(256, n - base);
        __syncthreads();
        if (t < chunk) sh[t] = perm[start + base + t];
        __syncthreads();
        int j = 0;
        for (; j + 8 <= chunk; j += 8) {
            const int r0 = sh[j+0], r1 = sh[j+1], r2 = sh[j+2], r3 = sh[j+3];
            const int r4 = sh[j+4], r5 = sh[j+5], r6 = sh[j+6], r7 = sh[j+7];
            const float2 v0 = f2[(size_t)r0 * N_FEAT2 + t];
            const float2 v1 = f2[(size_t)r1 * N_FEAT2 + t];
            const float2 v2 = f2[(size_t)r2 * N_FEAT2 + t];
            const float2 v3 = f2[(size_t)r3 * N_FEAT2 + t];
            const float2 v4 = f2[(size_t)r4 * N_FEAT2 + t];
            const float2 v5 = f2[(size_t)r5 * N_FEAT2 + t];
            const float2 v6 = f2[(size_t)r6 * N_FEAT2 + t];
            const float2 v7 = f2[(size_t)r7 * N_FEAT2 + t];
            sx += v0.x; sy += v0.y; qx += v0.x*v0.x; qy += v0.y*v0.y;
            sx += v1.x; sy += v1.y; qx += v1.x*v1.x; qy += v1.y*v1.y;
            sx += v2.x; sy += v2.y; qx += v2.x*v2.x; qy += v2.y*v2.y;
            sx += v3.x; sy += v3.y; qx += v3.x*v3.x; qy += v3.y*v3.y;
            sx += v4.x; sy += v4.y; qx += v4.x*v4.x; qy += v4.y*v4.y;
            sx += v5.x; sy += v5.y; qx += v5.x*v5.x; qy += v5.y*v5.y;
            sx += v6.x; sy += v6.y; qx += v6.x*v6.x; qy += v6.y*v6.y;
            sx += v7.x; sy += v7.y; qx += v7.x*v7.x; qy += v7.y*v7.y;
        }
        for (; j < chunk; ++j) {
            const float2 v = f2[(size_t)sh[j] * N_FEAT2 + t];
            sx += v.x; sy += v.y; qx += v.x*v.x; qy += v.y*v.y;
        }
    }

    const float fn  = (float)n;
    const float amt = (n > 0) ? fn : 1.0f;
    const float inv = 1.0f / amt;
    const float avx = sx * inv, avy = sy * inv;
    const float vrx = qx * inv - avx * avx;   // E[x^2]-E[x]^2 == segsum((x-ave)^2)/amt
    const float vry = qy * inv - avy * avy;

    const float cnt   = count[c];
    const float denom = fn + cnt;
    const float w     = (denom == 0.f) ? 0.f : fn / denom;
    const float omw   = 1.0f - w;

    const float2 mv = ((const float2*)mean)[c * N_FEAT2 + t];
    const float2 cv = ((const float2*)cov)[c * N_FEAT2 + t];
    const float dx = mv.x - avx, dy = mv.y - avy;

    float2 covn, meann;
    covn.x  = cv.x * omw + vrx * w + w * omw * dx * dx;
    covn.y  = cv.y * omw + vry * w + w * omw * dy * dy;
    meann.x = mv.x * omw + avx * w;
    meann.y = mv.y * omw + avy * w;

    ((float2*)out)[c * N_FEAT2 + t] = covn;                      // cov_new  [C,A]
    ((float2*)(out + N_CLS * N_FEAT))[c * N_FEAT2 + t] = meann;  // mean_new [C,A]
    if (t == 0) out[2 * N_CLS * N_FEAT + c] = cnt + fn;          // count_new [C]
}

extern "C" void kernel_launch(void* const* d_in, const int* in_sizes, int n_in,
                              void* d_out, int out_size, void* d_ws, size_t ws_size,
                              hipStream_t stream) {
    const float* features = (const float*)d_in[0];
    const int*   labels   = (const int*)d_in[1];
    const float* count    = (const float*)d_in[2];
    const float* mean     = (const float*)d_in[3];
    const float* cov      = (const float*)d_in[4];
    float* out = (float*)d_out;

    char* ws = (char*)d_ws;
    int* offs   = (int*)(ws + 0);       // 1025 ints (8 KB slot)
    int* cursor = (int*)(ws + 8192);    // 1024 ints
    int* perm   = (int*)(ws + 12288);   // 65536 ints

    hist_scan_kernel<<<1, 1024, 0, stream>>>(labels, offs, cursor);
    scatter_kernel<<<N_ROWS / 4 / 256, 256, 0, stream>>>(labels, cursor, perm);
    estimator_main<<<N_CLS, 256, 0, stream>>>(features, count, mean, cov,
                                              offs, perm, out);
}

// Round 4
// 226.767 us; speedup vs baseline: 2.5360x; 1.0303x over previous
//
#include <hip/hip_runtime.h>

// Problem constants (from reference): N=65536 rows, A=512 features, C=1000 classes.
constexpr int N_ROWS  = 65536;
constexpr int N_FEAT  = 512;
constexpr int N_FEAT4 = N_FEAT / 4;   // float4 per row = 128
constexpr int N_CLS   = 1000;

// Workspace layout (bytes):
//   [0,     4096)   int bins[1024]     per-class counts (memsetAsync to 0)
//   [4096, 12288)   int offs[1025]     exclusive prefix offsets
//   [12288,16384)   int cursor[1024]   scatter cursors
//   [16384, ...)    int perm[65536]    row indices grouped by class

// ---- Kernel 1: multi-block histogram (LDS-local, then global merge) ----
__global__ __launch_bounds__(256) void hist_kernel(
    const int* __restrict__ labels, int* __restrict__ bins)
{
    __shared__ int lbins[1024];
    const int t = threadIdx.x;
    lbins[t] = 0; lbins[t+256] = 0; lbins[t+512] = 0; lbins[t+768] = 0;
    __syncthreads();
    const int4 v = ((const int4*)labels)[blockIdx.x * 256 + t];
    atomicAdd(&lbins[v.x], 1); atomicAdd(&lbins[v.y], 1);
    atomicAdd(&lbins[v.z], 1); atomicAdd(&lbins[v.w], 1);
    __syncthreads();
    for (int i = t; i < N_CLS; i += 256) {
        int c = lbins[i];
        if (c) atomicAdd(&bins[i], c);
    }
}

// ---- Kernel 2: exclusive scan over 1024 bins (1 block; input is only 4 KB) ----
__global__ __launch_bounds__(1024) void scan_kernel(
    const int* __restrict__ bins, int* __restrict__ offs, int* __restrict__ cursor)
{
    __shared__ int tmp[1024];
    const int t = threadIdx.x;
    const int v = (t < N_CLS) ? bins[t] : 0;
    tmp[t] = v;
    __syncthreads();
    for (int d = 1; d < 1024; d <<= 1) {
        int x = (t >= d) ? tmp[t - d] : 0;
        __syncthreads();
        tmp[t] += x;
        __syncthreads();
    }
    const int excl = tmp[t] - v;
    offs[t] = excl;
    cursor[t] = excl;
    if (t == 0) offs[1024] = N_ROWS;
}

// ---- Kernel 3: scatter row indices grouped by class ----
__global__ __launch_bounds__(256) void scatter_kernel(
    const int* __restrict__ labels, int* __restrict__ cursor, int* __restrict__ perm)
{
    const int i = blockIdx.x * blockDim.x + threadIdx.x;   // one int4 (4 rows) per thread
    const int4 v = ((const int4*)labels)[i];
    const int r = i * 4;
    perm[atomicAdd(&cursor[v.x], 1)] = r + 0;
    perm[atomicAdd(&cursor[v.y], 1)] = r + 1;
    perm[atomicAdd(&cursor[v.z], 1)] = r + 2;
    perm[atomicAdd(&cursor[v.w], 1)] = r + 3;
}

// ---- Kernel 4: per-class reduction + fused epilogue ----
// One block per class. 256 threads: half = t>>7 selects row-within-pair, each
// thread owns 4 columns (float4, 16 B/lane = coalescing sweet spot; a wave
// covers 1 KB contiguous). 8 slots unrolled = 16 rows/iter = 8 outstanding
// 1 KB wave-loads. Cross-half LDS reduce, float4 epilogue by threads 0..127.
__global__ __launch_bounds__(256) void estimator_main(
    const float* __restrict__ features,
    const float* __restrict__ count,
    const float* __restrict__ mean,
    const float* __restrict__ cov,
    const int* __restrict__ offs,
    const int* __restrict__ perm,
    float* __restrict__ out)
{
    const int c = blockIdx.x;
    const int t = threadIdx.x;
    const int half = t >> 7;          // 0 or 1: which row of the pair
    const int col  = t & 127;         // float4 column index
    const int start = offs[c];
    const int n = offs[c + 1] - start;

    __shared__ int sh[256];
    __shared__ float4 red_s[128];
    __shared__ float4 red_q[128];

    const float4* __restrict__ f4 = (const float4*)features;

    float s0 = 0.f, s1 = 0.f, s2 = 0.f, s3 = 0.f;
    float q0 = 0.f, q1 = 0.f, q2 = 0.f, q3 = 0.f;

    for (int base = 0; base < n; base += 256) {
        const int chunk = min(256, n - base);
        __syncthreads();
        if (t < chunk) sh[t] = perm[start + base + t];
        __syncthreads();
        int j = 0;
        // full 16-row groups: 8 independent 16B loads per lane, no predication
        for (; j + 16 <= chunk; j += 16) {
            const int r0 = sh[j +  0 + half], r1 = sh[j +  2 + half];
            const int r2 = sh[j +  4 + half], r3 = sh[j +  6 + half];
            const int r4 = sh[j +  8 + half], r5 = sh[j + 10 + half];
            const int r6 = sh[j + 12 + half], r7 = sh[j + 14 + half];
            const float4 v0 = f4[(size_t)r0 * N_FEAT4 + col];
            const float4 v1 = f4[(size_t)r1 * N_FEAT4 + col];
            const float4 v2 = f4[(size_t)r2 * N_FEAT4 + col];
            const float4 v3 = f4[(size_t)r3 * N_FEAT4 + col];
            const float4 v4 = f4[(size_t)r4 * N_FEAT4 + col];
            const float4 v5 = f4[(size_t)r5 * N_FEAT4 + col];
            const float4 v6 = f4[(size_t)r6 * N_FEAT4 + col];
            const float4 v7 = f4[(size_t)r7 * N_FEAT4 + col];
            #define ACC(v) \
                s0 += v.x; q0 = fmaf(v.x, v.x, q0); \
                s1 += v.y; q1 = fmaf(v.y, v.y, q1); \
                s2 += v.z; q2 = fmaf(v.z, v.z, q2); \
                s3 += v.w; q3 = fmaf(v.w, v.w, q3);
            ACC(v0) ACC(v1) ACC(v2) ACC(v3) ACC(v4) ACC(v5) ACC(v6) ACC(v7)
            #undef ACC
        }
        // weighted remainder: up to 15 rows; invalid slots read a valid row with w=0
        if (j < chunk) {
            #pragma unroll
            for (int u = 0; u < 8; ++u) {
                const int idx = j + 2 * u + half;
                const int r = (idx < chunk) ? sh[idx] : sh[j];
                const float w = (idx < chunk) ? 1.f : 0.f;
                const float4 v = f4[(size_t)r * N_FEAT4 + col];
                const float vx = v.x * w, vy = v.y * w, vz = v.z * w, vw = v.w * w;
                s0 += vx; q0 = fmaf(vx, v.x, q0);
                s1 += vy; q1 = fmaf(vy, v.y, q1);
                s2 += vz; q2 = fmaf(vz, v.z, q2);
                s3 += vw; q3 = fmaf(vw, v.w, q3);
            }
        }
    }

    // cross-half reduce: half 1 -> LDS, half 0 accumulates
    __syncthreads();
    if (half == 1) {
        red_s[col] = make_float4(s0, s1, s2, s3);
        red_q[col] = make_float4(q0, q1, q2, q3);
    }
    __syncthreads();
    if (half == 0) {
        const float4 rs = red_s[col], rq = red_q[col];
        s0 += rs.x; s1 += rs.y; s2 += rs.z; s3 += rs.w;
        q0 += rq.x; q1 += rq.y; q2 += rq.z; q3 += rq.w;

        const float fn  = (float)n;
        const float amt = (n > 0) ? fn : 1.0f;
        const float inv = 1.0f / amt;
        const float a0 = s0 * inv, a1 = s1 * inv, a2 = s2 * inv, a3 = s3 * inv;
        const float vr0 = q0 * inv - a0 * a0;   // E[x^2]-E[x]^2 == segsum((x-ave)^2)/amt
        const float vr1 = q1 * inv - a1 * a1;
        const float vr2 = q2 * inv - a2 * a2;
        const float vr3 = q3 * inv - a3 * a3;

        const float cnt   = count[c];
        const float denom = fn + cnt;
        const float w     = (denom == 0.f) ? 0.f : fn / denom;
        const float omw   = 1.0f - w;

        const float4 mv = ((const float4*)mean)[c * N_FEAT4 + col];
        const float4 cv = ((const float4*)cov)[c * N_FEAT4 + col];
        const float d0 = mv.x - a0, d1 = mv.y - a1, d2 = mv.z - a2, d3 = mv.w - a3;

        float4 covn, meann;
        covn.x  = cv.x * omw + vr0 * w + w * omw * d0 * d0;
        covn.y  = cv.y * omw + vr1 * w + w * omw * d1 * d1;
        covn.z  = cv.z * omw + vr2 * w + w * omw * d2 * d2;
        covn.w  = cv.w * omw + vr3 * w + w * omw * d3 * d3;
        meann.x = mv.x * omw + a0 * w;
        meann.y = mv.y * omw + a1 * w;
        meann.z = mv.z * omw + a2 * w;
        meann.w = mv.w * omw + a3 * w;

        ((float4*)out)[c * N_FEAT4 + col] = covn;                      // cov_new  [C,A]
        ((float4*)(out + N_CLS * N_FEAT))[c * N_FEAT4 + col] = meann;  // mean_new [C,A]
        if (t == 0) out[2 * N_CLS * N_FEAT + c] = cnt + fn;            // count_new [C]
    }
}

extern "C" void kernel_launch(void* const* d_in, const int* in_sizes, int n_in,
                              void* d_out, int out_size, void* d_ws, size_t ws_size,
                              hipStream_t stream) {
    const float* features = (const float*)d_in[0];
    const int*   labels   = (const int*)d_in[1];
    const float* count    = (const float*)d_in[2];
    const float* mean     = (const float*)d_in[3];
    const float* cov      = (const float*)d_in[4];
    float* out = (float*)d_out;

    char* ws = (char*)d_ws;
    int* bins   = (int*)(ws + 0);       // 1024 ints
    int* offs   = (int*)(ws + 4096);    // 1025 ints
    int* cursor = (int*)(ws + 12288);   // 1024 ints
    int* perm   = (int*)(ws + 16384);   // 65536 ints

    hipMemsetAsync(bins, 0, 1024 * sizeof(int), stream);
    hist_kernel<<<N_ROWS / 4 / 256, 256, 0, stream>>>(labels, bins);
    scan_kernel<<<1, 1024, 0, stream>>>(bins, offs, cursor);
    scatter_kernel<<<N_ROWS / 4 / 256, 256, 0, stream>>>(labels, cursor, perm);
    estimator_main<<<N_CLS, 256, 0, stream>>>(features, count, mean, cov,
                                              offs, perm, out);
}